// Round 12
// baseline (1299.731 us; speedup 1.0000x reference)
//
#include <hip/hip_runtime.h>
#include <hip/hip_bf16.h>
#include <math.h>

constexpr int Bc   = 4;
constexpr int Nc   = 200;
constexpr int Cc   = 64;
constexpr int Mc   = 600;    // 3*N
constexpr int ATTc = 128;
constexpr int OUTFc = 128;
constexpr int PREDc = 12;
constexpr int MAXBW = 40;
constexpr int MPAD  = 640;   // padded V^T leading dim

typedef short short8 __attribute__((ext_vector_type(8)));
typedef float f32x4  __attribute__((ext_vector_type(4)));

static __device__ __forceinline__ void bsplit(float v, short& h, short& l) {
    __hip_bfloat16 hb = __float2bfloat16(v);
    float hf = __bfloat162float(hb);
    __hip_bfloat16 lb = __float2bfloat16(v - hf);
    h = *(short*)&hb; l = *(short*)&lb;
}

// ---------------- embed + sliding window ----------------
__global__ __launch_bounds__(256)
void embed_window_k(const float* __restrict__ src, const float* __restrict__ temb,
                    const float* __restrict__ semb, float* __restrict__ dst,
                    int Tin, int nw, long total)
{
    long idx = (long)blockIdx.x * 256 + threadIdx.x;
    if (idx >= total) return;
    int c = (int)(idx & 63);
    long r = idx >> 6;
    int n = (int)(r % Nc); r /= Nc;
    int j = (int)(r % 3);  r /= 3;
    int w = (int)(r % nw);
    int b = (int)(r / nw);
    int t = w + j;
    dst[idx] = src[(((long)b * Tin + t) * Nc + n) * Cc + c]
             + temb[t * Cc + c] + semb[n * Cc + c];
}

// ---------------- fused node-mean + NA/NB projection (16-row blocks) -------
__global__ __launch_bounds__(256)
void mean_nab_k(const float* __restrict__ cur, const float* __restrict__ Wa,
                const float* __restrict__ Wb, float* __restrict__ NA,
                float* __restrict__ NB, int BW)
{
    __shared__ float Ns[64][17];   // [k][row]
    __shared__ float Ws[64][132];  // [k][ Wa | Wb ]
    const int m0 = blockIdx.x * 16;
    const int t = threadIdx.x;
    for (int e = t; e < 1024; e += 256) {
        int r = e >> 4, c4 = (e & 15) << 2;
        *(float4*)&Ws[r][c4]      = *(const float4*)&Wa[r * 64 + c4];
        *(float4*)&Ws[r][64 + c4] = *(const float4*)&Wb[r * 64 + c4];
    }
    {
        int row = t >> 4, c4 = (t & 15) << 2;
        int gm = m0 + row;
        float4 sv = make_float4(0.f, 0.f, 0.f, 0.f);
        if (gm < Mc) {
            for (int bw = 0; bw < BW; bw++) {
                const float4 v = *(const float4*)&cur[((long)bw * Mc + gm) * Cc + c4];
                sv.x += v.x; sv.y += v.y; sv.z += v.z; sv.w += v.w;
            }
        }
        const float inv = 1.f / BW;
        Ns[c4 + 0][row] = sv.x * inv; Ns[c4 + 1][row] = sv.y * inv;
        Ns[c4 + 2][row] = sv.z * inv; Ns[c4 + 3][row] = sv.w * inv;
    }
    __syncthreads();
    const int row = t >> 4, c8 = (t & 15) * 8;
    float acc[8] = {};
    for (int k = 0; k < 64; k++) {
        float a = Ns[k][row];
        float b[8];
        *(float4*)&b[0] = *(const float4*)&Ws[k][c8];
        *(float4*)&b[4] = *(const float4*)&Ws[k][c8 + 4];
#pragma unroll
        for (int j = 0; j < 8; j++) acc[j] += a * b[j];
    }
    int gm = m0 + row;
    if (gm < Mc) {
#pragma unroll
        for (int j = 0; j < 8; j++) {
            int col = c8 + j;
            if (col < 64) NA[gm * 64 + col] = acc[j];
            else          NB[gm * 64 + col - 64] = acc[j];
        }
    }
}

// ---------------- 64-tile fp32 GEMM (adj, Wlin) ----------------
template<bool BT, int EPI>
__global__ __launch_bounds__(256)
void gemm_k(const float* __restrict__ A, const float* __restrict__ Bm,
            const float* __restrict__ bias, float* __restrict__ C,
            int M, int N, int K, int lda, int ldb, int ldc,
            long sA, long sB, long sC, float alpha)
{
    __shared__ float As[16][68];
    __shared__ float Bs[16][68];
    const int z = blockIdx.z;
    A  += (long)z * sA;
    Bm += (long)z * sB;
    C  += (long)z * sC;
    const int m0 = blockIdx.y * 64, n0 = blockIdx.x * 64;
    const int t = threadIdx.x;
    const int tx = t & 15, ty = t >> 4;
    float acc[4][4] = {};
    for (int k0 = 0; k0 < K; k0 += 16) {
        {
            int r = t >> 2, kb = (t & 3) << 2;
            int gm = m0 + r;
            const float* ap = A + (long)gm * lda + k0 + kb;
#pragma unroll
            for (int i = 0; i < 4; i++) {
                int gk = k0 + kb + i;
                As[kb + i][r] = (gm < M && gk < K) ? ap[i] : 0.f;
            }
        }
        if (!BT) {
            int nn = t & 63, kq = t >> 6;
#pragma unroll
            for (int i = 0; i < 4; i++) {
                int kk = kq * 4 + i;
                int gk = k0 + kk, gn = n0 + nn;
                Bs[kk][nn] = (gk < K && gn < N) ? Bm[(long)gk * ldb + gn] : 0.f;
            }
        } else {
            int nn = t >> 2, kb = (t & 3) << 2;
            int gn = n0 + nn;
            const float* bp = Bm + (long)gn * ldb + k0 + kb;
#pragma unroll
            for (int i = 0; i < 4; i++) {
                int gk = k0 + kb + i;
                Bs[kb + i][nn] = (gn < N && gk < K) ? bp[i] : 0.f;
            }
        }
        __syncthreads();
#pragma unroll
        for (int kk = 0; kk < 16; kk++) {
            const float4 a4 = *(const float4*)&As[kk][ty * 4];
            const float4 b4 = *(const float4*)&Bs[kk][tx * 4];
            const float a[4] = {a4.x, a4.y, a4.z, a4.w};
            const float b[4] = {b4.x, b4.y, b4.z, b4.w};
#pragma unroll
            for (int i = 0; i < 4; i++)
#pragma unroll
                for (int j = 0; j < 4; j++) acc[i][j] += a[i] * b[j];
        }
        __syncthreads();
    }
#pragma unroll
    for (int i = 0; i < 4; i++) {
        int gm = m0 + ty * 4 + i;
        if (gm >= M) continue;
#pragma unroll
        for (int j = 0; j < 4; j++) {
            int gn = n0 + tx * 4 + j;
            if (gn >= N) continue;
            float v = acc[i][j] * alpha;
            if (bias) v += bias[gn];
            if (EPI == 1) v = 1.f / (1.f + __expf(-v));
            if (EPI == 2) v = fmaxf(v, 0.f);
            C[(long)gm * ldc + gn] = v;
        }
    }
}

// ---------------- QKV GEMM -> hi/lo bf16 buffers (packed 16B stores) -------
__global__ __launch_bounds__(256)
void qkv_split_k(const float* __restrict__ CURp, const float* __restrict__ Wqkv,
                 const float* __restrict__ bias,
                 ushort* __restrict__ QH, ushort* __restrict__ QL,
                 ushort* __restrict__ KH, ushort* __restrict__ KL,
                 ushort* __restrict__ VTH, ushort* __restrict__ VTL)
{
    __shared__ float As[16][132];
    __shared__ float Bs[16][132];
    const int which = blockIdx.x;          // 0=q 1=k 2=v
    const int m0 = blockIdx.y * 128;
    const int z  = blockIdx.z;
    const float* A = CURp + (long)z * Mc * Cc;
    const int n0 = which * 128;
    const int t = threadIdx.x;
    const int tx = t & 15, ty = t >> 4;
    float acc[8][8] = {};

    for (int k0 = 0; k0 < 64; k0 += 16) {
#pragma unroll
        for (int pass = 0; pass < 2; pass++) {
            int e = t + pass * 256;
            int rr = e >> 2, kb = (e & 3) << 2;
            int gm = m0 + rr;
            float4 v = make_float4(0.f, 0.f, 0.f, 0.f);
            if (gm < Mc) v = *(const float4*)(A + (long)gm * 64 + k0 + kb);
            As[kb + 0][rr] = v.x; As[kb + 1][rr] = v.y;
            As[kb + 2][rr] = v.z; As[kb + 3][rr] = v.w;
        }
#pragma unroll
        for (int pass = 0; pass < 2; pass++) {
            int e = t + pass * 256;
            int kk = e >> 5, n4 = (e & 31) << 2;
            float4 v = *(const float4*)(Wqkv + (long)(k0 + kk) * 384 + n0 + n4);
            *(float4*)&Bs[kk][n4] = v;
        }
        __syncthreads();
#pragma unroll
        for (int kk = 0; kk < 16; kk++) {
            float a[8], b[8];
            *(float4*)&a[0] = *(const float4*)&As[kk][ty * 8];
            *(float4*)&a[4] = *(const float4*)&As[kk][ty * 8 + 4];
            *(float4*)&b[0] = *(const float4*)&Bs[kk][tx * 8];
            *(float4*)&b[4] = *(const float4*)&Bs[kk][tx * 8 + 4];
#pragma unroll
            for (int i = 0; i < 8; i++)
#pragma unroll
                for (int j = 0; j < 8; j++) acc[i][j] += a[i] * b[j];
        }
        __syncthreads();
    }

    if (which == 2) {
        if (m0 + ty * 8 < Mc) {
            ushort* vh = VTH + (long)z * ATTc * MPAD;
            ushort* vl = VTL + (long)z * ATTc * MPAD;
#pragma unroll
            for (int j = 0; j < 8; j++) {
                int col = tx * 8 + j;
                short8 h8, l8;
#pragma unroll
                for (int i = 0; i < 8; i++) {
                    float v = fmaxf(acc[i][j] + bias[n0 + col], 0.f);
                    short hs, ls;
                    bsplit(v, hs, ls);
                    h8[i] = hs; l8[i] = ls;
                }
                *(short8*)(vh + (long)col * MPAD + m0 + ty * 8) = h8;
                *(short8*)(vl + (long)col * MPAD + m0 + ty * 8) = l8;
            }
        }
    } else {
        ushort* dh = (which == 0 ? QH : KH) + (long)z * Mc * ATTc;
        ushort* dl = (which == 0 ? QL : KL) + (long)z * Mc * ATTc;
#pragma unroll
        for (int i = 0; i < 8; i++) {
            int row = m0 + ty * 8 + i;
            if (row >= Mc) continue;
            short8 h8, l8;
#pragma unroll
            for (int j = 0; j < 8; j++) {
                float v = acc[i][j] + bias[n0 + tx * 8 + j];
                short hs, ls;
                bsplit(v, hs, ls);
                h8[j] = hs; l8[j] = ls;
            }
            *(short8*)(dh + (long)row * ATTc + tx * 8) = h8;
            *(short8*)(dl + (long)row * ATTc + tx * 8) = l8;
        }
    }
}

// ---- fused attention v2: 32 q-rows/wave, K LDS-staged (prefetched), V ----
// direct-from-global frags, P in wave-private LDS, no-max softmax (exact).
// Grid BW*5, XCD-swizzled. Block = 128 q-rows, 4 waves x 32 rows.
__global__ __launch_bounds__(256, 1)
void attn_k(const ushort* __restrict__ QH, const ushort* __restrict__ QL,
            const ushort* __restrict__ KH, const ushort* __restrict__ KL,
            const ushort* __restrict__ VTH, const ushort* __restrict__ VTL,
            const float* __restrict__ adj, float* __restrict__ O, float scale)
{
    __shared__ __align__(16) ushort SB[2][128][72];   // K stage: 128 keys x 64 att
    __shared__ __align__(16) ushort PH[4][32][152];   // wave-private P hi
    __shared__ __align__(16) ushort PL[4][32][152];   //                lo
    const int bid = blockIdx.x;
    const int xcd = bid & 7, slot = bid >> 3;
    const int z = (slot / 5) * 8 + xcd;
    const int m0 = (slot % 5) * 128;
    const int t = threadIdx.x;
    const int lane = t & 63, w = t >> 6;
    const int lm = lane & 15, lq = lane >> 4;
    const int qrow0 = m0 + w * 32;

    const ushort* Qhz = QH + (long)z * Mc * ATTc;
    const ushort* Qlz = QL + (long)z * Mc * ATTc;
    const ushort* Khz = KH + (long)z * Mc * ATTc;
    const ushort* Klz = KL + (long)z * Mc * ATTc;
    const ushort* Vhz = VTH + (long)z * ATTc * MPAD;
    const ushort* Vlz = VTL + (long)z * ATTc * MPAD;

    // Q frags: 2 row-groups x 4 att-chunks, register-resident
    short8 qh[2][4], ql[2][4];
#pragma unroll
    for (int g = 0; g < 2; g++) {
        int qr = qrow0 + g * 16 + lm;
        if (qr < Mc) {
            const ushort* qp = Qhz + (long)qr * ATTc;
            const ushort* qp2 = Qlz + (long)qr * ATTc;
#pragma unroll
            for (int ks = 0; ks < 4; ks++) {
                qh[g][ks] = *(const short8*)(qp + ks * 32 + lq * 8);
                ql[g][ks] = *(const short8*)(qp2 + ks * 32 + lq * 8);
            }
        } else {
#pragma unroll
            for (int ks = 0; ks < 4; ks++)
#pragma unroll
                for (int q = 0; q < 8; q++) { qh[g][ks][q] = 0; ql[g][ks][q] = 0; }
        }
    }

    f32x4 oacc[2][8];
#pragma unroll
    for (int g = 0; g < 2; g++)
#pragma unroll
        for (int j = 0; j < 8; j++)
#pragma unroll
            for (int r = 0; r < 4; r++) oacc[g][j][r] = 0.f;
    float Er[2][4] = {}, Sr[2][4] = {};

    // K-stage prefetch registers
    short8 pre_h[4], pre_l[4];
    {   // prefetch chunk 0, g 0
#pragma unroll
        for (int p = 0; p < 4; p++) {
            int e = t + p * 256;
            int row = e >> 3, ks = (e & 7) << 3;
            short8 vh, vl;
#pragma unroll
            for (int q = 0; q < 8; q++) { vh[q] = 0; vl[q] = 0; }
            if (row < Mc) {
                vh = *(const short8*)(Khz + (long)row * ATTc + ks);
                vl = *(const short8*)(Klz + (long)row * ATTc + ks);
            }
            pre_h[p] = vh; pre_l[p] = vl;
        }
    }

    for (int kc = 0; kc < 640; kc += 128) {
        f32x4 sacc[2][8];
#pragma unroll
        for (int g = 0; g < 2; g++)
#pragma unroll
            for (int j = 0; j < 8; j++)
#pragma unroll
                for (int r = 0; r < 4; r++) sacc[g][j][r] = 0.f;

        // ---- QK: 2 staging rounds of 64 att ----
#pragma unroll
        for (int g = 0; g < 2; g++) {
            __syncthreads();
#pragma unroll
            for (int p = 0; p < 4; p++) {
                int e = t + p * 256;
                int row = e >> 3, ks = (e & 7) << 3;
                *(short8*)&SB[0][row][ks] = pre_h[p];
                *(short8*)&SB[1][row][ks] = pre_l[p];
            }
            __syncthreads();
            // prefetch next stage (hidden behind the MFMAs below)
            {
                int ng = g + 1, nkc = kc;
                if (ng == 2) { ng = 0; nkc = kc + 128; }
                if (nkc < 640) {
#pragma unroll
                    for (int p = 0; p < 4; p++) {
                        int e = t + p * 256;
                        int row = e >> 3, ks = (e & 7) << 3;
                        int key = nkc + row;
                        short8 vh, vl;
#pragma unroll
                        for (int q = 0; q < 8; q++) { vh[q] = 0; vl[q] = 0; }
                        if (key < Mc) {
                            vh = *(const short8*)(Khz + (long)key * ATTc + ng * 64 + ks);
                            vl = *(const short8*)(Klz + (long)key * ATTc + ng * 64 + ks);
                        }
                        pre_h[p] = vh; pre_l[p] = vl;
                    }
                }
            }
#pragma unroll
            for (int kk = 0; kk < 2; kk++) {
                int ks = g * 2 + kk;
#pragma unroll
                for (int j = 0; j < 8; j++) {
                    short8 bh = *(const short8*)&SB[0][j * 16 + lm][kk * 32 + lq * 8];
                    short8 bl = *(const short8*)&SB[1][j * 16 + lm][kk * 32 + lq * 8];
#pragma unroll
                    for (int g2 = 0; g2 < 2; g2++) {
                        sacc[g2][j] = __builtin_amdgcn_mfma_f32_16x16x32_bf16(qh[g2][ks], bh, sacc[g2][j], 0, 0, 0);
                        sacc[g2][j] = __builtin_amdgcn_mfma_f32_16x16x32_bf16(qh[g2][ks], bl, sacc[g2][j], 0, 0, 0);
                        sacc[g2][j] = __builtin_amdgcn_mfma_f32_16x16x32_bf16(ql[g2][ks], bh, sacc[g2][j], 0, 0, 0);
                    }
                }
            }
        }

        // ---- P = exp(s*scale)*adj -> wave-private LDS; accumulate E,S ----
#pragma unroll
        for (int g = 0; g < 2; g++)
#pragma unroll
            for (int j = 0; j < 8; j++) {
                int col = kc + j * 16 + lm;
                bool cok = col < Mc;
#pragma unroll
                for (int r = 0; r < 4; r++) {
                    int row = qrow0 + g * 16 + lq * 4 + r;
                    float e = cok ? __expf(sacc[g][j][r] * scale) : 0.f;
                    float a = (cok && row < Mc) ? adj[(long)row * Mc + col] : 0.f;
                    float p = e * a;
                    Er[g][r] += e; Sr[g][r] += p;
                    short hs, ls;
                    bsplit(p, hs, ls);
                    PH[w][g * 16 + lq * 4 + r][j * 16 + lm] = (ushort)hs;
                    PL[w][g * 16 + lq * 4 + r][j * 16 + lm] = (ushort)ls;
                }
            }

        // ---- PV: V frags direct from global (coalesced 16 rows x 64B) ----
#pragma unroll
        for (int kk = 0; kk < 4; kk++) {
            short8 ph[2], pl[2];
#pragma unroll
            for (int g = 0; g < 2; g++) {
                ph[g] = *(const short8*)&PH[w][g * 16 + lm][kk * 32 + lq * 8];
                pl[g] = *(const short8*)&PL[w][g * 16 + lm][kk * 32 + lq * 8];
            }
#pragma unroll
            for (int at = 0; at < 8; at++) {
                const long vo = (long)(at * 16 + lm) * MPAD + kc + kk * 32 + lq * 8;
                short8 vh = *(const short8*)(Vhz + vo);
                short8 vl = *(const short8*)(Vlz + vo);
#pragma unroll
                for (int g = 0; g < 2; g++) {
                    oacc[g][at] = __builtin_amdgcn_mfma_f32_16x16x32_bf16(ph[g], vh, oacc[g][at], 0, 0, 0);
                    oacc[g][at] = __builtin_amdgcn_mfma_f32_16x16x32_bf16(ph[g], vl, oacc[g][at], 0, 0, 0);
                    oacc[g][at] = __builtin_amdgcn_mfma_f32_16x16x32_bf16(pl[g], vh, oacc[g][at], 0, 0, 0);
                }
            }
        }
    }

    // ---- row sums across lm lanes, then scaled store ----
#pragma unroll
    for (int mk = 1; mk <= 8; mk <<= 1)
#pragma unroll
        for (int g = 0; g < 2; g++)
#pragma unroll
            for (int r = 0; r < 4; r++) {
                Er[g][r] += __shfl_xor(Er[g][r], mk, 64);
                Sr[g][r] += __shfl_xor(Sr[g][r], mk, 64);
            }
    float* Oz = O + (long)z * Mc * ATTc;
#pragma unroll
    for (int g = 0; g < 2; g++) {
        float inv[4];
#pragma unroll
        for (int r = 0; r < 4; r++) inv[r] = 1.f / (Sr[g][r] + 1e-8f * Er[g][r]);
#pragma unroll
        for (int at = 0; at < 8; at++)
#pragma unroll
            for (int r = 0; r < 4; r++) {
                int row = qrow0 + g * 16 + lq * 4 + r;
                if (row < Mc)
                    Oz[(long)row * ATTc + at * 16 + lm] = oacc[g][at][r] * inv[r];
            }
    }
}

// ---------------- running max of middle-window slice [2N:3N] ---------------
__global__ __launch_bounds__(256)
void cand_update_k(const float* __restrict__ cur, float* __restrict__ cand,
                   int bw0, long total, int first)
{
    long idx = (long)blockIdx.x * 256 + threadIdx.x;
    if (idx >= total) return;
    int c = (int)(idx & 63);
    long r = idx >> 6;
    int n = (int)(r % Nc);
    int i = (int)(r / Nc);
    long bw = bw0 + i;
    float v = cur[((bw * Mc) + 2 * Nc + n) * Cc + c];
    long o = ((bw * Nc) + n) * Cc + c;
    cand[o] = first ? v : fmaxf(cand[o], v);
}

// ---------------- output layer ----------------
__global__ __launch_bounds__(128)
void output_k(const float* __restrict__ h2, const float* __restrict__ Wo,
              const float* __restrict__ bo, float* __restrict__ out)
{
    __shared__ float ds[512];
    int row = blockIdx.x;
    int b = row / Nc, n = row % Nc;
    int t = threadIdx.x;
    for (int e = t; e < 512; e += 128) {
        int tt = e >> 6, c = e & 63;
        ds[e] = h2[(((long)b * 8 + tt) * Nc + n) * Cc + c];
    }
    __syncthreads();
    float acc = bo[t];
    for (int e = 0; e < 512; e++) acc += ds[e] * Wo[e * OUTFc + t];
    acc = fmaxf(acc, 0.f);
    for (int p = 0; p < PREDc; p++)
        out[(((long)b * PREDc + p) * Nc + n) * (long)OUTFc + t] = acc;
}

extern "C" void kernel_launch(void* const* d_in, const int* in_sizes, int n_in,
                              void* d_out, int out_size, void* d_ws, size_t ws_size,
                              hipStream_t stream)
{
    (void)in_sizes; (void)n_in; (void)out_size; (void)ws_size;
    const float* x     = (const float*)d_in[0];
    const float* Wqkv  = (const float*)d_in[4];
    const float* bqkv  = (const float*)d_in[5];
    const float* Wlin  = (const float*)d_in[6];
    const float* blin  = (const float*)d_in[7];
    const float* Wa    = (const float*)d_in[8];
    const float* Wb    = (const float*)d_in[9];
    const float* temb0 = (const float*)d_in[13];
    const float* temb1 = (const float*)d_in[14];
    const float* semb  = (const float*)d_in[15];
    const float* Wo    = (const float*)d_in[16];
    const float* bo    = (const float*)d_in[17];
    float* out = (float*)d_out;

    // ---- workspace (float offsets), ~60 MB ----
    float* ws   = (float*)d_ws;
    float* CUR  = ws;                                  // 1,536,000
    float* NA   = CUR + (long)MAXBW * Mc * Cc;
    float* NB   = NA + Mc * Cc;
    float* ADJ  = NB + Mc * Cc;                        // 360,000
    float* CAND = ADJ + (long)Mc * Mc;                 // 512,000
    float* ATTB = CAND + (long)MAXBW * Nc * Cc;        // 3,072,000
    float* QHf  = ATTB + (long)MAXBW * Mc * ATTc;
    const long QSZ = (long)MAXBW * Mc * ATTc / 2;      // in floats
    float* QLf  = QHf + QSZ;
    float* KHf  = QLf + QSZ;
    float* KLf  = KHf + QSZ;
    float* VTHf = KLf + QSZ;
    float* VTLf = VTHf + (long)MAXBW * ATTc * MPAD / 2;

    ushort* QH  = (ushort*)QHf;
    ushort* QL  = (ushort*)QLf;
    ushort* KH  = (ushort*)KHf;
    ushort* KL  = (ushort*)KLf;
    ushort* VTH = (ushort*)VTHf;
    ushort* VTL = (ushort*)VTLf;

    const float inv_sqrt_att = 0.08838834764831845f;   // 1/sqrt(128)

    for (int layer = 0; layer < 2; layer++) {
        int Tin = layer ? 10 : 12;
        int nw  = Tin - 2;
        int BW  = Bc * nw;                             // 40 then 32
        int Mtot = BW * Mc;
        const float* src  = layer ? CAND : x;
        const float* temb = layer ? temb1 : temb0;

        long etotal = (long)BW * Mc * Cc;
        embed_window_k<<<dim3((unsigned)((etotal + 255) / 256)), dim3(256), 0, stream>>>(
            src, temb, semb, CUR, Tin, nw, etotal);

        for (int it = 0; it < 3; it++) {
            // adjacency: mean -> NA/NB -> sigmoid(NA NB^T / 8)
            mean_nab_k<<<dim3(38), dim3(256), 0, stream>>>(CUR, Wa, Wb, NA, NB, BW);
            gemm_k<true, 1><<<dim3(10, 10, 1), dim3(256), 0, stream>>>(
                NA, NB, nullptr, ADJ, Mc, Mc, Cc, Cc, Cc, Mc, 0, 0, 0, 0.125f);

            // QKV projection + hi/lo split
            qkv_split_k<<<dim3(3, 5, BW), dim3(256), 0, stream>>>(
                CUR, Wqkv, bqkv, QH, QL, KH, KL, VTH, VTL);

            // fused attention (32 q-rows/wave, V direct, P in LDS)
            attn_k<<<dim3(BW * 5), dim3(256), 0, stream>>>(
                QH, QL, KH, KL, VTH, VTL, ADJ, ATTB, inv_sqrt_att);

            // cur = ATTB @ Wlin + blin
            gemm_k<false, 0><<<dim3(1, (Mtot + 63) / 64, 1), dim3(256), 0, stream>>>(
                ATTB, Wlin, blin, CUR, Mtot, Cc, ATTc, ATTc, Cc, Cc, 0, 0, 0, 1.f);

            // running max of middle window
            long mtot = (long)BW * Nc * Cc;
            cand_update_k<<<dim3((unsigned)((mtot + 255) / 256)), dim3(256), 0, stream>>>(
                CUR, CAND, 0, mtot, it == 0 ? 1 : 0);
        }
    }
    output_k<<<dim3(Bc * Nc), dim3(128), 0, stream>>>(CAND, Wo, bo, out);
}

// Round 13
// 924.094 us; speedup vs baseline: 1.4065x; 1.4065x over previous
//
#include <hip/hip_runtime.h>
#include <hip/hip_bf16.h>
#include <math.h>

constexpr int Bc   = 4;
constexpr int Nc   = 200;
constexpr int Cc   = 64;
constexpr int Mc   = 600;    // 3*N
constexpr int ATTc = 128;
constexpr int OUTFc = 128;
constexpr int PREDc = 12;
constexpr int MAXBW = 40;
constexpr int MPAD  = 640;   // padded V^T leading dim

typedef short short8 __attribute__((ext_vector_type(8)));
typedef float f32x4  __attribute__((ext_vector_type(4)));

static __device__ __forceinline__ void bsplit(float v, short& h, short& l) {
    __hip_bfloat16 hb = __float2bfloat16(v);
    float hf = __bfloat162float(hb);
    __hip_bfloat16 lb = __float2bfloat16(v - hf);
    h = *(short*)&hb; l = *(short*)&lb;
}

// ---------------- embed + sliding window ----------------
__global__ __launch_bounds__(256)
void embed_window_k(const float* __restrict__ src, const float* __restrict__ temb,
                    const float* __restrict__ semb, float* __restrict__ dst,
                    int Tin, int nw, long total)
{
    long idx = (long)blockIdx.x * 256 + threadIdx.x;
    if (idx >= total) return;
    int c = (int)(idx & 63);
    long r = idx >> 6;
    int n = (int)(r % Nc); r /= Nc;
    int j = (int)(r % 3);  r /= 3;
    int w = (int)(r % nw);
    int b = (int)(r / nw);
    int t = w + j;
    dst[idx] = src[(((long)b * Tin + t) * Nc + n) * Cc + c]
             + temb[t * Cc + c] + semb[n * Cc + c];
}

// ------- fused node-mean + NA/NB projection -> bf16 hi/lo outputs ---------
__global__ __launch_bounds__(256)
void mean_nab_k(const float* __restrict__ cur, const float* __restrict__ Wa,
                const float* __restrict__ Wb,
                ushort* __restrict__ NAH, ushort* __restrict__ NAL,
                ushort* __restrict__ NBH, ushort* __restrict__ NBL, int BW)
{
    __shared__ float Ns[64][17];   // [k][row]
    __shared__ float Ws[64][132];  // [k][ Wa | Wb ]
    const int m0 = blockIdx.x * 16;
    const int t = threadIdx.x;
    for (int e = t; e < 1024; e += 256) {
        int r = e >> 4, c4 = (e & 15) << 2;
        *(float4*)&Ws[r][c4]      = *(const float4*)&Wa[r * 64 + c4];
        *(float4*)&Ws[r][64 + c4] = *(const float4*)&Wb[r * 64 + c4];
    }
    {
        int row = t >> 4, c4 = (t & 15) << 2;
        int gm = m0 + row;
        float4 sv = make_float4(0.f, 0.f, 0.f, 0.f);
        if (gm < Mc) {
            for (int bw = 0; bw < BW; bw++) {
                const float4 v = *(const float4*)&cur[((long)bw * Mc + gm) * Cc + c4];
                sv.x += v.x; sv.y += v.y; sv.z += v.z; sv.w += v.w;
            }
        }
        const float inv = 1.f / BW;
        Ns[c4 + 0][row] = sv.x * inv; Ns[c4 + 1][row] = sv.y * inv;
        Ns[c4 + 2][row] = sv.z * inv; Ns[c4 + 3][row] = sv.w * inv;
    }
    __syncthreads();
    const int row = t >> 4, c8 = (t & 15) * 8;
    float acc[8] = {};
    for (int k = 0; k < 64; k++) {
        float a = Ns[k][row];
        float b[8];
        *(float4*)&b[0] = *(const float4*)&Ws[k][c8];
        *(float4*)&b[4] = *(const float4*)&Ws[k][c8 + 4];
#pragma unroll
        for (int j = 0; j < 8; j++) acc[j] += a * b[j];
    }
    int gm = m0 + row;
    if (gm < Mc) {
#pragma unroll
        for (int j = 0; j < 8; j++) {
            int col = c8 + j;
            short h, l;
            bsplit(acc[j], h, l);
            if (col < 64) { NAH[gm * 64 + col] = (ushort)h; NAL[gm * 64 + col] = (ushort)l; }
            else { NBH[gm * 64 + col - 64] = (ushort)h; NBL[gm * 64 + col - 64] = (ushort)l; }
        }
    }
}

// ---- adj = sigmoid( (NA NB^T) / 8 ): split-bf16 MFMA, 128-tiles, grid 5x5 -
__global__ __launch_bounds__(256)
void adjmm_k(const ushort* __restrict__ Ah, const ushort* __restrict__ Al,
             const ushort* __restrict__ Bh, const ushort* __restrict__ Bl,
             float* __restrict__ ADJ)
{
    __shared__ __align__(16) ushort As[2][128][40];
    __shared__ __align__(16) ushort Bs[2][128][40];
    const int m0 = blockIdx.y * 128, n0 = blockIdx.x * 128;
    const int t = threadIdx.x;
    const int lane = t & 63, w = t >> 6;
    const int wm = (w >> 1) * 64, wn = (w & 1) * 64;
    const int lm = lane & 15, lq = lane >> 4;

    f32x4 acc[4][4];
#pragma unroll
    for (int i = 0; i < 4; i++)
#pragma unroll
        for (int j = 0; j < 4; j++)
#pragma unroll
            for (int r = 0; r < 4; r++) acc[i][j][r] = 0.f;

    for (int k0 = 0; k0 < 64; k0 += 32) {
        __syncthreads();
#pragma unroll
        for (int p = 0; p < 2; p++) {
            int e = t + p * 256;
            int row = e >> 2, ks = (e & 3) << 3;
            {
                int gm = m0 + row;
                short8 vh, vl;
#pragma unroll
                for (int q = 0; q < 8; q++) { vh[q] = 0; vl[q] = 0; }
                if (gm < Mc) {
                    vh = *(const short8*)(Ah + (long)gm * 64 + k0 + ks);
                    vl = *(const short8*)(Al + (long)gm * 64 + k0 + ks);
                }
                *(short8*)&As[0][row][ks] = vh;
                *(short8*)&As[1][row][ks] = vl;
            }
            {
                int gn = n0 + row;
                short8 vh, vl;
#pragma unroll
                for (int q = 0; q < 8; q++) { vh[q] = 0; vl[q] = 0; }
                if (gn < Mc) {
                    vh = *(const short8*)(Bh + (long)gn * 64 + k0 + ks);
                    vl = *(const short8*)(Bl + (long)gn * 64 + k0 + ks);
                }
                *(short8*)&Bs[0][row][ks] = vh;
                *(short8*)&Bs[1][row][ks] = vl;
            }
        }
        __syncthreads();

        short8 af[4][2], bf[4][2];
#pragma unroll
        for (int i = 0; i < 4; i++) {
            af[i][0] = *(const short8*)&As[0][wm + i * 16 + lm][lq * 8];
            af[i][1] = *(const short8*)&As[1][wm + i * 16 + lm][lq * 8];
        }
#pragma unroll
        for (int j = 0; j < 4; j++) {
            bf[j][0] = *(const short8*)&Bs[0][wn + j * 16 + lm][lq * 8];
            bf[j][1] = *(const short8*)&Bs[1][wn + j * 16 + lm][lq * 8];
        }
#pragma unroll
        for (int i = 0; i < 4; i++)
#pragma unroll
            for (int j = 0; j < 4; j++) {
                acc[i][j] = __builtin_amdgcn_mfma_f32_16x16x32_bf16(af[i][0], bf[j][0], acc[i][j], 0, 0, 0);
                acc[i][j] = __builtin_amdgcn_mfma_f32_16x16x32_bf16(af[i][0], bf[j][1], acc[i][j], 0, 0, 0);
                acc[i][j] = __builtin_amdgcn_mfma_f32_16x16x32_bf16(af[i][1], bf[j][0], acc[i][j], 0, 0, 0);
            }
    }
#pragma unroll
    for (int i = 0; i < 4; i++) {
        int gmb = m0 + wm + i * 16 + lq * 4;
#pragma unroll
        for (int j = 0; j < 4; j++) {
            int gn = n0 + wn + j * 16 + lm;
            if (gn >= Mc) continue;
#pragma unroll
            for (int r = 0; r < 4; r++) {
                int gm = gmb + r;
                if (gm < Mc)
                    ADJ[(long)gm * Mc + gn] = 1.f / (1.f + __expf(-acc[i][j][r] * 0.125f));
            }
        }
    }
}

// ---------------- QKV GEMM -> hi/lo bf16 buffers, XCD-swizzled -------------
// 1-D grid BW*15: z pinned to XCD z%8 (matches attn's mapping).
__global__ __launch_bounds__(256)
void qkv_split_k(const float* __restrict__ CURp, const float* __restrict__ Wqkv,
                 const float* __restrict__ bias,
                 ushort* __restrict__ QH, ushort* __restrict__ QL,
                 ushort* __restrict__ KH, ushort* __restrict__ KL,
                 ushort* __restrict__ VTH, ushort* __restrict__ VTL)
{
    __shared__ float As[16][132];
    __shared__ float Bs[16][132];
    const int bid = blockIdx.x;
    const int xcd = bid & 7, slot = bid >> 3;
    const int z = (slot / 15) * 8 + xcd;
    const int r15 = slot % 15;
    const int which = r15 % 3;             // 0=q 1=k 2=v
    const int m0 = (r15 / 3) * 128;
    const float* A = CURp + (long)z * Mc * Cc;
    const int n0 = which * 128;
    const int t = threadIdx.x;
    const int tx = t & 15, ty = t >> 4;
    float acc[8][8] = {};

    for (int k0 = 0; k0 < 64; k0 += 16) {
#pragma unroll
        for (int pass = 0; pass < 2; pass++) {
            int e = t + pass * 256;
            int rr = e >> 2, kb = (e & 3) << 2;
            int gm = m0 + rr;
            float4 v = make_float4(0.f, 0.f, 0.f, 0.f);
            if (gm < Mc) v = *(const float4*)(A + (long)gm * 64 + k0 + kb);
            As[kb + 0][rr] = v.x; As[kb + 1][rr] = v.y;
            As[kb + 2][rr] = v.z; As[kb + 3][rr] = v.w;
        }
#pragma unroll
        for (int pass = 0; pass < 2; pass++) {
            int e = t + pass * 256;
            int kk = e >> 5, n4 = (e & 31) << 2;
            float4 v = *(const float4*)(Wqkv + (long)(k0 + kk) * 384 + n0 + n4);
            *(float4*)&Bs[kk][n4] = v;
        }
        __syncthreads();
#pragma unroll
        for (int kk = 0; kk < 16; kk++) {
            float a[8], b[8];
            *(float4*)&a[0] = *(const float4*)&As[kk][ty * 8];
            *(float4*)&a[4] = *(const float4*)&As[kk][ty * 8 + 4];
            *(float4*)&b[0] = *(const float4*)&Bs[kk][tx * 8];
            *(float4*)&b[4] = *(const float4*)&Bs[kk][tx * 8 + 4];
#pragma unroll
            for (int i = 0; i < 8; i++)
#pragma unroll
                for (int j = 0; j < 8; j++) acc[i][j] += a[i] * b[j];
        }
        __syncthreads();
    }

    if (which == 2) {
        if (m0 + ty * 8 < Mc) {
            ushort* vh = VTH + (long)z * ATTc * MPAD;
            ushort* vl = VTL + (long)z * ATTc * MPAD;
#pragma unroll
            for (int j = 0; j < 8; j++) {
                int col = tx * 8 + j;
                short8 h8, l8;
#pragma unroll
                for (int i = 0; i < 8; i++) {
                    float v = fmaxf(acc[i][j] + bias[n0 + col], 0.f);
                    short hs, ls;
                    bsplit(v, hs, ls);
                    h8[i] = hs; l8[i] = ls;
                }
                *(short8*)(vh + (long)col * MPAD + m0 + ty * 8) = h8;
                *(short8*)(vl + (long)col * MPAD + m0 + ty * 8) = l8;
            }
        }
    } else {
        ushort* dh = (which == 0 ? QH : KH) + (long)z * Mc * ATTc;
        ushort* dl = (which == 0 ? QL : KL) + (long)z * Mc * ATTc;
#pragma unroll
        for (int i = 0; i < 8; i++) {
            int row = m0 + ty * 8 + i;
            if (row >= Mc) continue;
            short8 h8, l8;
#pragma unroll
            for (int j = 0; j < 8; j++) {
                float v = acc[i][j] + bias[n0 + tx * 8 + j];
                short hs, ls;
                bsplit(v, hs, ls);
                h8[j] = hs; l8[j] = ls;
            }
            *(short8*)(dh + (long)row * ATTc + tx * 8) = h8;
            *(short8*)(dl + (long)row * ATTc + tx * 8) = l8;
        }
    }
}

// ---- fused attention (R11-proven config): S=QK^T -> P=exp(s)*adj -> PV ----
// Grid BW*10 XCD-swizzled, 64 q-rows/block, 4 waves x 16 rows, K/V LDS-staged,
// P wave-private. O stored as packed bf16 hi/lo pairs (uint32) for wlin MFMA.
__global__ __launch_bounds__(256)
void attn_k(const ushort* __restrict__ QH, const ushort* __restrict__ QL,
            const ushort* __restrict__ KH, const ushort* __restrict__ KL,
            const ushort* __restrict__ VTH, const ushort* __restrict__ VTL,
            const float* __restrict__ adj, uint* __restrict__ OB, float scale)
{
    __shared__ __align__(16) ushort SB[2][128][72];   // K or V stage (64 k)
    __shared__ __align__(16) ushort PH[4][16][152];   // wave-private P hi
    __shared__ __align__(16) ushort PL[4][16][152];   //                lo
    const int bid = blockIdx.x;
    const int xcd = bid & 7, slot = bid >> 3;
    const int z = (slot / 10) * 8 + xcd;
    const int m0 = (slot % 10) * 64;
    const int t = threadIdx.x;
    const int lane = t & 63, w = t >> 6;
    const int lm = lane & 15, lq = lane >> 4;
    const int qrow0 = m0 + w * 16;

    const ushort* Qhz = QH + (long)z * Mc * ATTc;
    const ushort* Qlz = QL + (long)z * Mc * ATTc;
    const ushort* Khz = KH + (long)z * Mc * ATTc;
    const ushort* Klz = KL + (long)z * Mc * ATTc;
    const ushort* Vhz = VTH + (long)z * ATTc * MPAD;
    const ushort* Vlz = VTL + (long)z * ATTc * MPAD;

    short8 qh[4], ql[4];
    {
        int qr = qrow0 + lm;
        if (qr < Mc) {
            const ushort* qp = Qhz + (long)qr * ATTc;
            const ushort* qp2 = Qlz + (long)qr * ATTc;
#pragma unroll
            for (int ks = 0; ks < 4; ks++) {
                qh[ks] = *(const short8*)(qp + ks * 32 + lq * 8);
                ql[ks] = *(const short8*)(qp2 + ks * 32 + lq * 8);
            }
        } else {
#pragma unroll
            for (int ks = 0; ks < 4; ks++)
#pragma unroll
                for (int q = 0; q < 8; q++) { qh[ks][q] = 0; ql[ks][q] = 0; }
        }
    }

    f32x4 oacc[8];
#pragma unroll
    for (int j = 0; j < 8; j++)
#pragma unroll
        for (int r = 0; r < 4; r++) oacc[j][r] = 0.f;
    float Er[4] = {}, Sr[4] = {};

    for (int kc = 0; kc < 640; kc += 128) {       // 5 key chunks
        f32x4 sacc[8];
#pragma unroll
        for (int j = 0; j < 8; j++)
#pragma unroll
            for (int r = 0; r < 4; r++) sacc[j][r] = 0.f;

        // ---- QK phase: 2 staging rounds of 64 att ----
#pragma unroll
        for (int g = 0; g < 2; g++) {
            __syncthreads();
#pragma unroll
            for (int p = 0; p < 4; p++) {
                int e = t + p * 256;              // 0..1023
                int row = e >> 3, ks = (e & 7) << 3;
                int key = kc + row;
                short8 vh, vl;
#pragma unroll
                for (int q = 0; q < 8; q++) { vh[q] = 0; vl[q] = 0; }
                if (key < Mc) {
                    vh = *(const short8*)(Khz + (long)key * ATTc + g * 64 + ks);
                    vl = *(const short8*)(Klz + (long)key * ATTc + g * 64 + ks);
                }
                *(short8*)&SB[0][row][ks] = vh;
                *(short8*)&SB[1][row][ks] = vl;
            }
            __syncthreads();
#pragma unroll
            for (int kk = 0; kk < 2; kk++) {
                int ks = g * 2 + kk;
#pragma unroll
                for (int j = 0; j < 8; j++) {
                    short8 bh = *(const short8*)&SB[0][j * 16 + lm][kk * 32 + lq * 8];
                    short8 bl = *(const short8*)&SB[1][j * 16 + lm][kk * 32 + lq * 8];
                    sacc[j] = __builtin_amdgcn_mfma_f32_16x16x32_bf16(qh[ks], bh, sacc[j], 0, 0, 0);
                    sacc[j] = __builtin_amdgcn_mfma_f32_16x16x32_bf16(qh[ks], bl, sacc[j], 0, 0, 0);
                    sacc[j] = __builtin_amdgcn_mfma_f32_16x16x32_bf16(ql[ks], bh, sacc[j], 0, 0, 0);
                }
            }
        }

        // ---- epilogue: P = exp(s*scale)*adj -> wave-private LDS ----
#pragma unroll
        for (int j = 0; j < 8; j++) {
            int col = kc + j * 16 + lm;
            bool cok = col < Mc;
#pragma unroll
            for (int r = 0; r < 4; r++) {
                int row = qrow0 + lq * 4 + r;
                float e = cok ? __expf(sacc[j][r] * scale) : 0.f;
                float a = (cok && row < Mc) ? adj[(long)row * Mc + col] : 0.f;
                float p = e * a;
                Er[r] += e; Sr[r] += p;
                short hs, ls;
                bsplit(p, hs, ls);
                PH[w][lq * 4 + r][j * 16 + lm] = (ushort)hs;
                PL[w][lq * 4 + r][j * 16 + lm] = (ushort)ls;
            }
        }

        // ---- PV phase: 2 staging rounds of 64 keys ----
#pragma unroll
        for (int g = 0; g < 2; g++) {
            __syncthreads();
#pragma unroll
            for (int p = 0; p < 4; p++) {
                int e = t + p * 256;
                int att = e >> 3, ks = (e & 7) << 3;
                int key = kc + g * 64 + ks;       // < 640 = MPAD, always in buf
                short8 vh = *(const short8*)(Vhz + (long)att * MPAD + key);
                short8 vl = *(const short8*)(Vlz + (long)att * MPAD + key);
                *(short8*)&SB[0][att][ks] = vh;
                *(short8*)&SB[1][att][ks] = vl;
            }
            __syncthreads();
#pragma unroll
            for (int kk = 0; kk < 2; kk++) {
                short8 ph = *(const short8*)&PH[w][lm][g * 64 + kk * 32 + lq * 8];
                short8 pl = *(const short8*)&PL[w][lm][g * 64 + kk * 32 + lq * 8];
#pragma unroll
                for (int j = 0; j < 8; j++) {
                    short8 vh = *(const short8*)&SB[0][j * 16 + lm][kk * 32 + lq * 8];
                    short8 vl = *(const short8*)&SB[1][j * 16 + lm][kk * 32 + lq * 8];
                    oacc[j] = __builtin_amdgcn_mfma_f32_16x16x32_bf16(ph, vh, oacc[j], 0, 0, 0);
                    oacc[j] = __builtin_amdgcn_mfma_f32_16x16x32_bf16(ph, vl, oacc[j], 0, 0, 0);
                    oacc[j] = __builtin_amdgcn_mfma_f32_16x16x32_bf16(pl, vh, oacc[j], 0, 0, 0);
                }
            }
        }
    }

    // ---- row sums, then packed bf16 hi/lo store ----
#pragma unroll
    for (int mk = 1; mk <= 8; mk <<= 1)
#pragma unroll
        for (int r = 0; r < 4; r++) {
            Er[r] += __shfl_xor(Er[r], mk, 64);
            Sr[r] += __shfl_xor(Sr[r], mk, 64);
        }
    float inv[4];
#pragma unroll
    for (int r = 0; r < 4; r++) inv[r] = 1.f / (Sr[r] + 1e-8f * Er[r]);
    uint* Oz = OB + (long)z * Mc * ATTc;
#pragma unroll
    for (int j = 0; j < 8; j++)
#pragma unroll
        for (int r = 0; r < 4; r++) {
            int row = qrow0 + lq * 4 + r;
            if (row < Mc) {
                float v = oacc[j][r] * inv[r];
                short hs, ls;
                bsplit(v, hs, ls);
                Oz[(long)row * ATTc + j * 16 + lm] =
                    ((uint)(ushort)ls << 16) | (uint)(ushort)hs;
            }
        }
}

// ---------------- Wlin^T prep: transpose + bf16 hi/lo split ----------------
__global__ __launch_bounds__(256)
void wlin_prep_k(const float* __restrict__ Wlin,
                 ushort* __restrict__ WTH, ushort* __restrict__ WTL)
{
    int i = blockIdx.x * 256 + threadIdx.x;
    if (i >= 64 * 128) return;
    int c = i >> 7, a = i & 127;
    short h, l;
    bsplit(Wlin[a * 64 + c], h, l);
    WTH[c * 128 + a] = (ushort)h;
    WTL[c * 128 + a] = (ushort)l;
}

// ---- Wlin GEMM: CUR = unpack(OB) @ Wlin + blin (split-bf16 MFMA) ----------
// A: packed uint OB [Mtot][128]. B: WlinT hi/lo [64][128]. BM=128, BN=64.
__global__ __launch_bounds__(256)
void wlin_k(const uint* __restrict__ OB, const ushort* __restrict__ WTH,
            const ushort* __restrict__ WTL, const float* __restrict__ blin,
            float* __restrict__ CUR, int Mtot)
{
    __shared__ __align__(16) ushort As[2][128][40];
    __shared__ __align__(16) ushort Bs[2][64][136];
    const int m0 = blockIdx.x * 128;
    const int t = threadIdx.x;
    const int lane = t & 63, w = t >> 6;
    const int wm = (w >> 1) * 64, wn = (w & 1) * 32;
    const int lm = lane & 15, lq = lane >> 4;

    // stage all of B (64 x 128, hi+lo) once
#pragma unroll
    for (int p = 0; p < 4; p++) {
        int e = t + p * 256;
        int row = e >> 4, seg = (e & 15) << 3;
        *(short8*)&Bs[0][row][seg] = *(const short8*)(WTH + row * 128 + seg);
        *(short8*)&Bs[1][row][seg] = *(const short8*)(WTL + row * 128 + seg);
    }

    f32x4 acc[4][2];
#pragma unroll
    for (int i = 0; i < 4; i++)
#pragma unroll
        for (int j = 0; j < 2; j++)
#pragma unroll
            for (int r = 0; r < 4; r++) acc[i][j][r] = 0.f;

    for (int k0 = 0; k0 < 128; k0 += 32) {
        __syncthreads();
#pragma unroll
        for (int p = 0; p < 2; p++) {
            int e = t + p * 256;
            int row = e >> 2, seg = (e & 3) << 3;
            int gm = m0 + row;
            short8 vh, vl;
#pragma unroll
            for (int q = 0; q < 8; q++) { vh[q] = 0; vl[q] = 0; }
            if (gm < Mtot) {
                const uint4 u0 = *(const uint4*)(OB + (long)gm * 128 + k0 + seg);
                const uint4 u1 = *(const uint4*)(OB + (long)gm * 128 + k0 + seg + 4);
#pragma unroll
                for (int q = 0; q < 4; q++) {
                    uint u = ((const uint*)&u0)[q];
                    vh[q] = (short)(u & 0xffff); vl[q] = (short)(u >> 16);
                }
#pragma unroll
                for (int q = 0; q < 4; q++) {
                    uint u = ((const uint*)&u1)[q];
                    vh[4 + q] = (short)(u & 0xffff); vl[4 + q] = (short)(u >> 16);
                }
            }
            *(short8*)&As[0][row][seg] = vh;
            *(short8*)&As[1][row][seg] = vl;
        }
        __syncthreads();

        short8 af[4][2], bf[2][2];
#pragma unroll
        for (int i = 0; i < 4; i++) {
            af[i][0] = *(const short8*)&As[0][wm + i * 16 + lm][lq * 8];
            af[i][1] = *(const short8*)&As[1][wm + i * 16 + lm][lq * 8];
        }
#pragma unroll
        for (int j = 0; j < 2; j++) {
            bf[j][0] = *(const short8*)&Bs[0][wn + j * 16 + lm][k0 + lq * 8];
            bf[j][1] = *(const short8*)&Bs[1][wn + j * 16 + lm][k0 + lq * 8];
        }
#pragma unroll
        for (int i = 0; i < 4; i++)
#pragma unroll
            for (int j = 0; j < 2; j++) {
                acc[i][j] = __builtin_amdgcn_mfma_f32_16x16x32_bf16(af[i][0], bf[j][0], acc[i][j], 0, 0, 0);
                acc[i][j] = __builtin_amdgcn_mfma_f32_16x16x32_bf16(af[i][0], bf[j][1], acc[i][j], 0, 0, 0);
                acc[i][j] = __builtin_amdgcn_mfma_f32_16x16x32_bf16(af[i][1], bf[j][0], acc[i][j], 0, 0, 0);
            }
    }
#pragma unroll
    for (int i = 0; i < 4; i++) {
        int gmb = m0 + wm + i * 16 + lq * 4;
#pragma unroll
        for (int j = 0; j < 2; j++) {
            int col = wn + j * 16 + lm;
            float b = blin[col];
#pragma unroll
            for (int r = 0; r < 4; r++) {
                int gm = gmb + r;
                if (gm < Mtot) CUR[(long)gm * 64 + col] = acc[i][j][r] + b;
            }
        }
    }
}

// ---------------- running max of middle-window slice [2N:3N] ---------------
__global__ __launch_bounds__(256)
void cand_update_k(const float* __restrict__ cur, float* __restrict__ cand,
                   int bw0, long total, int first)
{
    long idx = (long)blockIdx.x * 256 + threadIdx.x;
    if (idx >= total) return;
    int c = (int)(idx & 63);
    long r = idx >> 6;
    int n = (int)(r % Nc);
    int i = (int)(r / Nc);
    long bw = bw0 + i;
    float v = cur[((bw * Mc) + 2 * Nc + n) * Cc + c];
    long o = ((bw * Nc) + n) * Cc + c;
    cand[o] = first ? v : fmaxf(cand[o], v);
}

// ---------------- output layer ----------------
__global__ __launch_bounds__(128)
void output_k(const float* __restrict__ h2, const float* __restrict__ Wo,
              const float* __restrict__ bo, float* __restrict__ out)
{
    __shared__ float ds[512];
    int row = blockIdx.x;
    int b = row / Nc, n = row % Nc;
    int t = threadIdx.x;
    for (int e = t; e < 512; e += 128) {
        int tt = e >> 6, c = e & 63;
        ds[e] = h2[(((long)b * 8 + tt) * Nc + n) * Cc + c];
    }
    __syncthreads();
    float acc = bo[t];
    for (int e = 0; e < 512; e++) acc += ds[e] * Wo[e * OUTFc + t];
    acc = fmaxf(acc, 0.f);
    for (int p = 0; p < PREDc; p++)
        out[(((long)b * PREDc + p) * Nc + n) * (long)OUTFc + t] = acc;
}

extern "C" void kernel_launch(void* const* d_in, const int* in_sizes, int n_in,
                              void* d_out, int out_size, void* d_ws, size_t ws_size,
                              hipStream_t stream)
{
    (void)in_sizes; (void)n_in; (void)out_size; (void)ws_size;
    const float* x     = (const float*)d_in[0];
    const float* Wqkv  = (const float*)d_in[4];
    const float* bqkv  = (const float*)d_in[5];
    const float* Wlin  = (const float*)d_in[6];
    const float* blin  = (const float*)d_in[7];
    const float* Wa    = (const float*)d_in[8];
    const float* Wb    = (const float*)d_in[9];
    const float* temb0 = (const float*)d_in[13];
    const float* temb1 = (const float*)d_in[14];
    const float* semb  = (const float*)d_in[15];
    const float* Wo    = (const float*)d_in[16];
    const float* bo    = (const float*)d_in[17];
    float* out = (float*)d_out;

    // ---- workspace (float offsets), ~60 MB ----
    float* ws   = (float*)d_ws;
    float* CUR  = ws;                                  // 1,536,000
    float* ADJ  = CUR + (long)MAXBW * Mc * Cc;         // 360,000
    float* CAND = ADJ + (long)Mc * Mc;                 // 512,000
    uint*  OB   = (uint*)(CAND + (long)MAXBW * Nc * Cc); // 3,072,000 u32
    float* QHf  = (float*)(OB + (long)MAXBW * Mc * ATTc);
    const long QSZ = (long)MAXBW * Mc * ATTc / 2;      // in floats
    float* QLf  = QHf + QSZ;
    float* KHf  = QLf + QSZ;
    float* KLf  = KHf + QSZ;
    float* VTHf = KLf + QSZ;
    float* VTLf = VTHf + (long)MAXBW * ATTc * MPAD / 2;
    ushort* NAH = (ushort*)(VTLf + (long)MAXBW * ATTc * MPAD / 2);
    ushort* NAL = NAH + Mc * Cc;
    ushort* NBH = NAL + Mc * Cc;
    ushort* NBL = NBH + Mc * Cc;
    ushort* WTH = NBL + Mc * Cc;                       // 64*128 each
    ushort* WTL = WTH + 64 * 128;

    ushort* QH  = (ushort*)QHf;
    ushort* QL  = (ushort*)QLf;
    ushort* KH  = (ushort*)KHf;
    ushort* KL  = (ushort*)KLf;
    ushort* VTH = (ushort*)VTHf;
    ushort* VTL = (ushort*)VTLf;

    const float inv_sqrt_att = 0.08838834764831845f;   // 1/sqrt(128)

    // Wlin^T hi/lo (weights constant across iterations)
    wlin_prep_k<<<dim3(32), dim3(256), 0, stream>>>(Wlin, WTH, WTL);

    for (int layer = 0; layer < 2; layer++) {
        int Tin = layer ? 10 : 12;
        int nw  = Tin - 2;
        int BW  = Bc * nw;                             // 40 then 32
        int Mtot = BW * Mc;
        const float* src  = layer ? CAND : x;
        const float* temb = layer ? temb1 : temb0;

        long etotal = (long)BW * Mc * Cc;
        embed_window_k<<<dim3((unsigned)((etotal + 255) / 256)), dim3(256), 0, stream>>>(
            src, temb, semb, CUR, Tin, nw, etotal);

        for (int it = 0; it < 3; it++) {
            // adjacency: mean -> NA/NB (bf16 split) -> sigmoid MFMA
            mean_nab_k<<<dim3(38), dim3(256), 0, stream>>>(
                CUR, Wa, Wb, NAH, NAL, NBH, NBL, BW);
            adjmm_k<<<dim3(5, 5), dim3(256), 0, stream>>>(
                NAH, NAL, NBH, NBL, ADJ);

            // QKV projection + hi/lo split (XCD-swizzled)
            qkv_split_k<<<dim3(BW * 15), dim3(256), 0, stream>>>(
                CUR, Wqkv, bqkv, QH, QL, KH, KL, VTH, VTL);

            // fused attention (R11 config), O stored packed bf16 hi/lo
            attn_k<<<dim3(BW * 10), dim3(256), 0, stream>>>(
                QH, QL, KH, KL, VTH, VTL, ADJ, OB, inv_sqrt_att);

            // cur = O @ Wlin + blin (split-bf16 MFMA)
            wlin_k<<<dim3((Mtot + 127) / 128), dim3(256), 0, stream>>>(
                OB, WTH, WTL, blin, CUR, Mtot);

            // running max of middle window
            long mtot = (long)BW * Nc * Cc;
            cand_update_k<<<dim3((unsigned)((mtot + 255) / 256)), dim3(256), 0, stream>>>(
                CUR, CAND, 0, mtot, it == 0 ? 1 : 0);
        }
    }
    output_k<<<dim3(Bc * Nc), dim3(128), 0, stream>>>(CAND, Wo, bo, out);
}